// Round 3
// baseline (433.320 us; speedup 1.0000x reference)
//
#include <hip/hip_runtime.h>

typedef _Float16 half8 __attribute__((ext_vector_type(8)));
typedef _Float16 half4t __attribute__((ext_vector_type(4)));
typedef _Float16 half2t __attribute__((ext_vector_type(2)));
typedef float float4t __attribute__((ext_vector_type(4)));
typedef float float4u __attribute__((ext_vector_type(4), aligned(4)));

#define BATCH 32
#define CIN 64
#define HIN 128
#define WIN 128
#define COUT 128
#define HOUT 126
#define WOUT 126
#define HP 63
#define WP 63
#define NGROUPS 16
#define CPG 8
#define EPSV 1e-5f

// xp row: 130 cols x 64 cins fp16 = 16640 B (8320 elems)
#define XPR 8320
#define XPRB 16640
#define STRIP 6   // oy rows per conv block (even, 126 = 21*6)

// wT[pos][cout][cin] fp16, pos = kh*3+kw
__global__ __launch_bounds__(256) void wt_kernel(const float* __restrict__ w,
                                                 _Float16* __restrict__ wT) {
    int idx = blockIdx.x * 256 + threadIdx.x;
    if (idx >= 9 * COUT * CIN) return;
    int cin = idx & 63;
    int t = idx >> 6;
    int cout = t & 127;
    int pos = t >> 7;
    wT[idx] = (_Float16)w[(cout * CIN + cin) * 9 + pos];
}

// Repack x NCHW fp32 -> xp[b][grow][col(130)][cin(64)] fp16, PRE-SWIZZLED:
// cin-chunk chk (8 cins) of (grow,col) stored at slot chk ^ ((2*grow+col)&7).
// LDS transpose: half2 b32 writes (4-way), conflict-free b32 reads.
__global__ __launch_bounds__(256) void repack_kernel(const float* __restrict__ x,
                                                     _Float16* __restrict__ xp) {
    __shared__ _Float16 lt[128 * 66];   // [col][cin], stride 66
    const int tid = threadIdx.x;
    const int grow = blockIdx.x;
    const int b = blockIdx.y;

    const int u = tid >> 5;             // 0..7
    const int col0 = (tid & 31) * 4;
    const float* xb = x + ((size_t)b * CIN * HIN + grow) * WIN;
#pragma unroll
    for (int i = 0; i < 4; i++) {
        int cin0 = 2 * (u + 8 * i);
        float4t va = *(const float4t*)(xb + (size_t)cin0 * HIN * WIN + col0);
        float4t vb = *(const float4t*)(xb + (size_t)(cin0 + 1) * HIN * WIN + col0);
#pragma unroll
        for (int j = 0; j < 4; j++) {
            half2t hv = { (_Float16)va[j], (_Float16)vb[j] };
            *(half2t*)&lt[(col0 + j) * 66 + cin0] = hv;   // b32, 4-way conflict
        }
    }
    __syncthreads();

    _Float16* xpb = xp + ((size_t)b * HIN + grow) * XPR;
#pragma unroll
    for (int k = 0; k < 16; k++) {
        int cidx = tid + 256 * k;        // 0..4095 -> (col 0..127, pair 0..31)
        int col = cidx >> 5, p = cidx & 31;
        half2t v = *(const half2t*)&lt[col * 66 + 2 * p];   // conflict-free
        int slot = (p >> 2) ^ ((2 * grow + col) & 7);
        *(half2t*)(xpb + col * 64 + slot * 8 + (p & 3) * 2) = v;
    }
    if (tid < 16) {                      // pad cols 128,129 = zeros
        int col = 128 + (tid >> 3), chk = tid & 7;
        int slot = chk ^ ((2 * grow + col) & 7);
        half8 z;
#pragma unroll
        for (int j = 0; j < 8; j++) z[j] = (_Float16)0.f;
        *(half8*)(xpb + col * 64 + slot * 8) = z;
    }
}

// Conv: strip of 6 oy rows per block, 4-slot rolling LDS row ring (66,560 B).
// Waves: w2 = couts 64*w2.., nh = pixel half. Per kk: 4 x-frags from LDS (disjoint
// per nh), 4 weight frags from L2-hot wT (prefetch ring). Epilogue pools 2x2
// in-register (max+min) and stores pooled fp16 pairs; stats accumulated per block.
__global__ __launch_bounds__(256, 2) void conv_mfma_kernel(
    const _Float16* __restrict__ xp, const _Float16* __restrict__ wT,
    const float* __restrict__ bias, unsigned int* __restrict__ pl,
    float* __restrict__ stats)
{
    __shared__ __align__(16) _Float16 xs[4 * XPR];   // 66,560 B

    const int tid = threadIdx.x;
    const int s = blockIdx.x;
    const int b = blockIdx.y;
    const int R0 = STRIP * s;

    const int lane = tid & 63;
    const int wv = tid >> 6;
    const int w2 = wv & 1;        // cout half
    const int nh = wv >> 1;       // pixel half
    const int m = lane & 15;
    const int q = lane >> 4;
    const int cb = w2 * 64;

    auto stage = [&](int r) {
        const char* src = (const char*)(xp + ((size_t)b * HIN + r) * XPR);
        char* dst = (char*)xs + (r & 3) * XPRB;
#pragma unroll
        for (int k = 0; k < 4; k++) {
            int off = (wv * 4 + k) * 1024;
            __builtin_amdgcn_global_load_lds(
                (const __attribute__((address_space(1))) void*)(src + off + lane * 16),
                (__attribute__((address_space(3))) void*)(dst + off), 16, 0, 0);
        }
        if (wv == 0) {
            __builtin_amdgcn_global_load_lds(
                (const __attribute__((address_space(1))) void*)(src + 16384 + lane * 4),
                (__attribute__((address_space(3))) void*)(dst + 16384), 4, 0, 0);
        }
    };

    stage(R0); stage(R0 + 1); stage(R0 + 2);

    half8 a[4], na[4];
#pragma unroll
    for (int sub = 0; sub < 4; sub++)
        a[sub] = *(const half8*)(wT + ((size_t)(cb + sub * 16 + m)) * CIN + q * 8);

    float bv[4];
#pragma unroll
    for (int sub = 0; sub < 4; sub++) bv[sub] = bias[cb + sub * 16 + m];

    float sv[4] = {0.f, 0.f, 0.f, 0.f}, ssv[4] = {0.f, 0.f, 0.f, 0.f};
    half4t prow[4][4];

    __syncthreads();

    for (int i = 0; i < STRIP; i++) {
        const int r = R0 + i;
        if (i < STRIP - 1) stage(r + 3);

        float4t acc[4][4];
#pragma unroll
        for (int sub = 0; sub < 4; sub++)
#pragma unroll
            for (int n = 0; n < 4; n++)
                acc[sub][n] = (float4t){0.f, 0.f, 0.f, 0.f};

        for (int kk = 0; kk < 18; kk++) {
            int pos = kk >> 1, ch = kk & 1;
            int kh = (pos > 2) + (pos > 5);
            int kw = pos - kh * 3;
            int rr = r + kh;
            int key = (2 * rr + m + kw) & 7;
            const _Float16* bb = &xs[(rr & 3) * XPR + (m + kw) * 64 + (((q + 4 * ch) ^ key) << 3)];

            int nk = (kk == 17) ? 0 : kk + 1;   // wrap: prefetch next row's kk=0
            int npos = nk >> 1, nch = nk & 1;
#pragma unroll
            for (int sub = 0; sub < 4; sub++)
                na[sub] = *(const half8*)(wT + ((size_t)(npos * COUT + cb + sub * 16 + m)) * CIN + q * 8 + nch * 32);

#pragma unroll
            for (int n = 0; n < 4; n++) {
                half8 bf = *(const half8*)(bb + (nh * 4 + n) * 1024);
#pragma unroll
                for (int sub = 0; sub < 4; sub++)
                    acc[sub][n] = __builtin_amdgcn_mfma_f32_16x16x32_f16(bf, a[sub], acc[sub][n], 0, 0, 0);
            }
#pragma unroll
            for (int sub = 0; sub < 4; sub++) a[sub] = na[sub];
        }

        // ---- epilogue: bias, stats accumulate, in-register 2x2 pool ----
        const bool odd = (i & 1) != 0;
#pragma unroll
        for (int sub = 0; sub < 4; sub++) {
#pragma unroll
            for (int n = 0; n < 4; n++) {
                int pix0 = (nh * 4 + n) * 16 + q * 4;
                float v0 = acc[sub][n][0] + bv[sub];
                float v1 = acc[sub][n][1] + bv[sub];
                float v2 = acc[sub][n][2] + bv[sub];
                float v3 = acc[sub][n][3] + bv[sub];
                sv[sub] += v0 + v1;
                ssv[sub] += v0 * v0 + v1 * v1;
                if (pix0 != 124) {      // only (nh=1,n=3,q=3) has pixels 126/127 invalid
                    sv[sub] += v2 + v3;
                    ssv[sub] += v2 * v2 + v3 * v3;
                }
                _Float16 x0 = (_Float16)fmaxf(v0, v1), n0 = (_Float16)fminf(v0, v1);
                _Float16 x1 = (_Float16)fmaxf(v2, v3), n1 = (_Float16)fminf(v2, v3);
                if (!odd) {
                    prow[sub][n] = (half4t){x0, n0, x1, n1};
                } else {
                    half4t p = prow[sub][n];
                    half4t o = { p[0] > x0 ? p[0] : x0, p[1] < n0 ? p[1] : n0,
                                 p[2] > x1 ? p[2] : x1, p[3] < n1 ? p[3] : n1 };
                    int c = cb + sub * 16 + m;
                    unsigned int* dst = pl + (((size_t)b * COUT + c) * HP + (r >> 1)) * 64
                                        + (nh * 4 + n) * 8 + 2 * q;
                    *(half4t*)dst = o;   // 8B; pooled col 63 garbage, never read
                }
            }
        }
        __syncthreads();
    }

    // ---- stats: reduce over lane bits {0,1,2,4,5}, atomic once per block ----
#pragma unroll
    for (int sub = 0; sub < 4; sub++) {
        float aa = sv[sub], cc = ssv[sub];
        aa += __shfl_xor(aa, 1);  cc += __shfl_xor(cc, 1);
        aa += __shfl_xor(aa, 2);  cc += __shfl_xor(cc, 2);
        aa += __shfl_xor(aa, 4);  cc += __shfl_xor(cc, 4);
        aa += __shfl_xor(aa, 16); cc += __shfl_xor(cc, 16);
        aa += __shfl_xor(aa, 32); cc += __shfl_xor(cc, 32);
        if ((lane & 55) == 0) {   // lanes 0 and 8
            int g = w2 * 8 + sub * 2 + ((lane >> 3) & 1);
            atomicAdd(&stats[(b * NGROUPS + g) * 2 + 0], aa);
            atomicAdd(&stats[(b * NGROUPS + g) * 2 + 1], cc);
        }
    }
}

// pl entry = half2 {mx, mn} per pooled col (64 per row, col 63 pad).
// out = max(A*mx+B, A*mn+B) handles either sign of A exactly.
__global__ __launch_bounds__(256) void norm_pool_kernel(
    const unsigned int* __restrict__ pl, const float* __restrict__ stats,
    const float* __restrict__ gnw, const float* __restrict__ gnb,
    const float* __restrict__ scale, float* __restrict__ out)
{
    const int t  = threadIdx.x & 15;        // pooled cols 4t..4t+3
    const int hs = threadIdx.x >> 4;
    const int hblk = blockIdx.x & 3;
    const int c = (blockIdx.x >> 2) & 127;
    const int b = blockIdx.x >> 9;
    const int hp = hblk * 16 + hs;

    const float N = (float)(CPG * HOUT * WOUT);
    int g = c >> 3;
    float sum   = stats[(b * NGROUPS + g) * 2 + 0];
    float sumsq = stats[(b * NGROUPS + g) * 2 + 1];
    float mean = sum / N;
    float var  = sumsq / N - mean * mean;
    float rstd = rsqrtf(var + EPSV);

    float gw = gnw[c] * rstd;
    float A  = gw * scale[c];
    float B2 = (gnb[c] - mean * gw) * scale[c];

    if (hp >= HP) return;

    const unsigned int* yp = pl + (((size_t)b * COUT + c) * HP + hp) * 64 + t * 4;
    half8 rv = *(const half8*)yp;   // 4 entries = {mx,mn}x4

    float o[4];
#pragma unroll
    for (int j = 0; j < 4; j++) {
        float vx = fmaf((float)rv[2 * j],     A, B2);
        float vn = fmaf((float)rv[2 * j + 1], A, B2);
        float mx = fmaxf(vx, vn);
        o[j] = fminf(fmaxf(mx, 0.0f), 1.0f);
    }

    float* op = out + (((size_t)b * COUT + c) * HP + hp) * WP + t * 4;
    if (t < 15) {
        *(float4u*)op = (float4u){o[0], o[1], o[2], o[3]};
    } else {          // pooled cols 60,61,62 valid; 63 is pad
        op[0] = o[0]; op[1] = o[1]; op[2] = o[2];
    }
}

extern "C" void kernel_launch(void* const* d_in, const int* in_sizes, int n_in,
                              void* d_out, int out_size, void* d_ws, size_t ws_size,
                              hipStream_t stream) {
    const float* x      = (const float*)d_in[0];
    const float* conv_w = (const float*)d_in[1];
    const float* conv_b = (const float*)d_in[2];
    const float* gnw    = (const float*)d_in[3];
    const float* gnb    = (const float*)d_in[4];
    const float* scale  = (const float*)d_in[5];
    float* out = (float*)d_out;

    const size_t pl_bytes = (size_t)BATCH * COUT * HP * 64 * 4;   // 66.1 MB
    unsigned int* pl = (unsigned int*)d_ws;
    float* stats = (float*)((char*)d_ws + pl_bytes);              // 4 KB reserved
    _Float16* wT = (_Float16*)((char*)d_ws + pl_bytes + 4096);    // 147,456 B
    _Float16* xp = (_Float16*)((char*)d_ws + pl_bytes + 4096 + 147456); // 68.2 MB

    hipMemsetAsync(stats, 0, BATCH * NGROUPS * 2 * sizeof(float), stream);

    wt_kernel<<<(9 * COUT * CIN + 255) / 256, 256, 0, stream>>>(conv_w, wT);

    dim3 rgrid(HIN, BATCH);
    repack_kernel<<<rgrid, 256, 0, stream>>>(x, xp);

    dim3 grid(HOUT / STRIP, BATCH);   // 21 x 32
    conv_mfma_kernel<<<grid, 256, 0, stream>>>(xp, wT, conv_b, pl, stats);

    norm_pool_kernel<<<BATCH * COUT * 4, 256, 0, stream>>>(
        pl, stats, gnw, gnb, scale, out);
}

// Round 4
// 365.072 us; speedup vs baseline: 1.1869x; 1.1869x over previous
//
#include <hip/hip_runtime.h>

typedef _Float16 half8 __attribute__((ext_vector_type(8)));
typedef _Float16 half4t __attribute__((ext_vector_type(4)));
typedef _Float16 half2t __attribute__((ext_vector_type(2)));
typedef float float4t __attribute__((ext_vector_type(4)));
typedef float float4u __attribute__((ext_vector_type(4), aligned(4)));

#define BATCH 32
#define CIN 64
#define HIN 128
#define WIN 128
#define COUT 128
#define HOUT 126
#define WOUT 126
#define HP 63
#define WP 63
#define NGROUPS 16
#define CPG 8
#define EPSV 1e-5f

// xp row: 130 cols x 64 cins fp16 = 16640 B (8320 elems)
#define XPR 8320
#define XPRB 16640

// wT[pos][cout][cin] fp16, pos = kh*3+kw
__global__ __launch_bounds__(256) void wt_kernel(const float* __restrict__ w,
                                                 _Float16* __restrict__ wT) {
    int idx = blockIdx.x * 256 + threadIdx.x;
    if (idx >= 9 * COUT * CIN) return;
    int cin = idx & 63;
    int t = idx >> 6;
    int cout = t & 127;
    int pos = t >> 7;
    wT[idx] = (_Float16)w[(cout * CIN + cin) * 9 + pos];
}

// Repack x NCHW fp32 -> xp[b][grow][col(130)][cin(64)] fp16, PRE-SWIZZLED:
// cin-chunk chk (8 cins) of (grow,col) stored at slot chk ^ ((2*grow+col)&7).
__global__ __launch_bounds__(256) void repack_kernel(const float* __restrict__ x,
                                                     _Float16* __restrict__ xp) {
    __shared__ _Float16 lt[128 * 66];   // [col][cin], stride 66
    const int tid = threadIdx.x;
    const int grow = blockIdx.x;
    const int b = blockIdx.y;

    const int u = tid >> 5;             // 0..7
    const int col0 = (tid & 31) * 4;
    const float* xb = x + ((size_t)b * CIN * HIN + grow) * WIN;
#pragma unroll
    for (int i = 0; i < 4; i++) {
        int cin0 = 2 * (u + 8 * i);
        float4t va = *(const float4t*)(xb + (size_t)cin0 * HIN * WIN + col0);
        float4t vb = *(const float4t*)(xb + (size_t)(cin0 + 1) * HIN * WIN + col0);
#pragma unroll
        for (int j = 0; j < 4; j++) {
            half2t hv = { (_Float16)va[j], (_Float16)vb[j] };
            *(half2t*)&lt[(col0 + j) * 66 + cin0] = hv;   // b32, 4-way conflict
        }
    }
    __syncthreads();

    _Float16* xpb = xp + ((size_t)b * HIN + grow) * XPR;
#pragma unroll
    for (int k = 0; k < 16; k++) {
        int cidx = tid + 256 * k;        // 0..4095 -> (col 0..127, pair 0..31)
        int col = cidx >> 5, p = cidx & 31;
        half2t v = *(const half2t*)&lt[col * 66 + 2 * p];   // conflict-free
        int slot = (p >> 2) ^ ((2 * grow + col) & 7);
        *(half2t*)(xpb + col * 64 + slot * 8 + (p & 3) * 2) = v;
    }
    if (tid < 16) {                      // pad cols 128,129 = zeros
        int col = 128 + (tid >> 3), chk = tid & 7;
        int slot = chk ^ ((2 * grow + col) & 7);
        half8 z;
#pragma unroll
        for (int j = 0; j < 8; j++) z[j] = (_Float16)0.f;
        *(half8*)(xpb + col * 64 + slot * 8) = z;
    }
}

// Conv: 2 output rows (one pooled row) per block. Stage 4 xp rows (66,560 B),
// ONE barrier, both rows computed in the same kk loop (weights shared -> weight
// loads halved vs 1-row blocks). Epilogue: bias, stats, full 2x2 pool in-register,
// store pooled {max,min} fp16 pairs. Grid 63 x 32 = 2016 blocks, 2 blocks/CU.
__global__ __launch_bounds__(256, 2) void conv_mfma_kernel(
    const _Float16* __restrict__ xp, const _Float16* __restrict__ wT,
    const float* __restrict__ bias, unsigned int* __restrict__ pl,
    float* __restrict__ stats)
{
    __shared__ __align__(16) _Float16 xs[4 * XPR];   // 66,560 B

    const int tid = threadIdx.x;
    // XCD-chunked remap (bijective: 2016 = 8*252; each XCD gets 4 full b's)
    int f = blockIdx.y * 63 + blockIdx.x;
    int w = (f & 7) * 252 + (f >> 3);
    const int s = w % 63;
    const int b = w / 63;
    const int oy = 2 * s;

    const int lane = tid & 63;
    const int wv = tid >> 6;
    const int w2 = wv & 1;        // cout half
    const int nh = wv >> 1;       // pixel half
    const int m = lane & 15;
    const int q = lane >> 4;
    const int cb = w2 * 64;

    // ---- stage: wave wv copies xp row oy+wv -> xs[wv] (16,640 B/wave) ----
    {
        const char* src = (const char*)(xp + ((size_t)b * HIN + oy + wv) * XPR);
        char* dst = (char*)xs + wv * XPRB;
#pragma unroll
        for (int k = 0; k < 16; k++) {
            __builtin_amdgcn_global_load_lds(
                (const __attribute__((address_space(1))) void*)(src + k * 1024 + lane * 16),
                (__attribute__((address_space(3))) void*)(dst + k * 1024), 16, 0, 0);
        }
        __builtin_amdgcn_global_load_lds(
            (const __attribute__((address_space(1))) void*)(src + 16384 + lane * 4),
            (__attribute__((address_space(3))) void*)(dst + 16384), 4, 0, 0);
    }

    half8 a[4], na[4];
#pragma unroll
    for (int sub = 0; sub < 4; sub++)
        a[sub] = *(const half8*)(wT + ((size_t)(cb + sub * 16 + m)) * CIN + q * 8);

    float bv[4];
#pragma unroll
    for (int sub = 0; sub < 4; sub++) bv[sub] = bias[cb + sub * 16 + m];

    float4t acc0[4][4], acc1[4][4];
#pragma unroll
    for (int sub = 0; sub < 4; sub++)
#pragma unroll
        for (int n = 0; n < 4; n++) {
            acc0[sub][n] = (float4t){0.f, 0.f, 0.f, 0.f};
            acc1[sub][n] = (float4t){0.f, 0.f, 0.f, 0.f};
        }

    __syncthreads();

    for (int kk = 0; kk < 18; kk++) {
        int pos = kk >> 1, ch = kk & 1;
        int kh = (pos > 2) + (pos > 5);
        int kw = pos - kh * 3;
        int key0 = (2 * (oy + kh) + m + kw) & 7;        // row oy+kh   -> xs[kh]
        int key1 = (key0 + 2) & 7;                      // row oy+1+kh -> xs[kh+1]
        const _Float16* b0 = &xs[kh * XPR + (m + kw) * 64 + (((q + 4 * ch) ^ key0) << 3)];
        const _Float16* b1 = &xs[(kh + 1) * XPR + (m + kw) * 64 + (((q + 4 * ch) ^ key1) << 3)];

#pragma unroll
        for (int sub = 0; sub < 4; sub++) na[sub] = a[sub];
        if (kk < 17) {
            int nk = kk + 1, npos = nk >> 1, nch = nk & 1;
#pragma unroll
            for (int sub = 0; sub < 4; sub++)
                na[sub] = *(const half8*)(wT + ((size_t)(npos * COUT + cb + sub * 16 + m)) * CIN + q * 8 + nch * 32);
        }

#pragma unroll
        for (int n = 0; n < 4; n++) {
            half8 bf0 = *(const half8*)(b0 + (nh * 4 + n) * 1024);
            half8 bf1 = *(const half8*)(b1 + (nh * 4 + n) * 1024);
#pragma unroll
            for (int sub = 0; sub < 4; sub++) {
                acc0[sub][n] = __builtin_amdgcn_mfma_f32_16x16x32_f16(bf0, a[sub], acc0[sub][n], 0, 0, 0);
                acc1[sub][n] = __builtin_amdgcn_mfma_f32_16x16x32_f16(bf1, a[sub], acc1[sub][n], 0, 0, 0);
            }
        }
#pragma unroll
        for (int sub = 0; sub < 4; sub++) a[sub] = na[sub];
    }

    // ---- epilogue: bias, stats (both rows), 2x2 pool -> {max,min} fp16 pairs ----
    float sv[4] = {0.f, 0.f, 0.f, 0.f}, ssv[4] = {0.f, 0.f, 0.f, 0.f};
#pragma unroll
    for (int sub = 0; sub < 4; sub++) {
        const int c = cb + sub * 16 + m;
#pragma unroll
        for (int n = 0; n < 4; n++) {
            int pix0 = (nh * 4 + n) * 16 + q * 4;
            float p00 = acc0[sub][n][0] + bv[sub];
            float p01 = acc0[sub][n][1] + bv[sub];
            float p02 = acc0[sub][n][2] + bv[sub];
            float p03 = acc0[sub][n][3] + bv[sub];
            float p10 = acc1[sub][n][0] + bv[sub];
            float p11 = acc1[sub][n][1] + bv[sub];
            float p12 = acc1[sub][n][2] + bv[sub];
            float p13 = acc1[sub][n][3] + bv[sub];
            sv[sub]  += p00 + p01 + p10 + p11;
            ssv[sub] += p00 * p00 + p01 * p01 + p10 * p10 + p11 * p11;
            if (pix0 != 124) {      // only (nh=1,n=3,q=3): pixels 126/127 invalid
                sv[sub]  += p02 + p03 + p12 + p13;
                ssv[sub] += p02 * p02 + p03 * p03 + p12 * p12 + p13 * p13;
            }
            float mx0 = fmaxf(fmaxf(p00, p01), fmaxf(p10, p11));
            float mn0 = fminf(fminf(p00, p01), fminf(p10, p11));
            float mx1 = fmaxf(fmaxf(p02, p03), fmaxf(p12, p13));
            float mn1 = fminf(fminf(p02, p03), fminf(p12, p13));
            half4t o = { (_Float16)mx0, (_Float16)mn0, (_Float16)mx1, (_Float16)mn1 };
            unsigned int* dst = pl + (((size_t)b * COUT + c) * HP + s) * 64
                                + (nh * 4 + n) * 8 + 2 * q;
            *(half4t*)dst = o;      // 8B; pooled col 63 garbage, never read
        }
    }

    // ---- stats: reduce over lane bits {0,1,2,4,5}, atomic once per block ----
#pragma unroll
    for (int sub = 0; sub < 4; sub++) {
        float aa = sv[sub], cc = ssv[sub];
        aa += __shfl_xor(aa, 1);  cc += __shfl_xor(cc, 1);
        aa += __shfl_xor(aa, 2);  cc += __shfl_xor(cc, 2);
        aa += __shfl_xor(aa, 4);  cc += __shfl_xor(cc, 4);
        aa += __shfl_xor(aa, 16); cc += __shfl_xor(cc, 16);
        aa += __shfl_xor(aa, 32); cc += __shfl_xor(cc, 32);
        if ((lane & 55) == 0) {   // lanes 0 and 8
            int g = w2 * 8 + sub * 2 + ((lane >> 3) & 1);
            atomicAdd(&stats[(b * NGROUPS + g) * 2 + 0], aa);
            atomicAdd(&stats[(b * NGROUPS + g) * 2 + 1], cc);
        }
    }
}

// pl entry = half2 {mx, mn} per pooled col. out = max(A*mx+B, A*mn+B): exact for
// either sign of A.
__global__ __launch_bounds__(256) void norm_pool_kernel(
    const unsigned int* __restrict__ pl, const float* __restrict__ stats,
    const float* __restrict__ gnw, const float* __restrict__ gnb,
    const float* __restrict__ scale, float* __restrict__ out)
{
    const int t  = threadIdx.x & 15;        // pooled cols 4t..4t+3
    const int hs = threadIdx.x >> 4;
    const int hblk = blockIdx.x & 3;
    const int c = (blockIdx.x >> 2) & 127;
    const int b = blockIdx.x >> 9;
    const int hp = hblk * 16 + hs;

    const float N = (float)(CPG * HOUT * WOUT);
    int g = c >> 3;
    float sum   = stats[(b * NGROUPS + g) * 2 + 0];
    float sumsq = stats[(b * NGROUPS + g) * 2 + 1];
    float mean = sum / N;
    float var  = sumsq / N - mean * mean;
    float rstd = rsqrtf(var + EPSV);

    float gw = gnw[c] * rstd;
    float A  = gw * scale[c];
    float B2 = (gnb[c] - mean * gw) * scale[c];

    if (hp >= HP) return;

    const unsigned int* yp = pl + (((size_t)b * COUT + c) * HP + hp) * 64 + t * 4;
    half8 rv = *(const half8*)yp;   // 4 entries = {mx,mn}x4

    float o[4];
#pragma unroll
    for (int j = 0; j < 4; j++) {
        float vx = fmaf((float)rv[2 * j],     A, B2);
        float vn = fmaf((float)rv[2 * j + 1], A, B2);
        float mx = fmaxf(vx, vn);
        o[j] = fminf(fmaxf(mx, 0.0f), 1.0f);
    }

    float* op = out + (((size_t)b * COUT + c) * HP + hp) * WP + t * 4;
    if (t < 15) {
        *(float4u*)op = (float4u){o[0], o[1], o[2], o[3]};
    } else {          // pooled cols 60,61,62 valid; 63 is pad
        op[0] = o[0]; op[1] = o[1]; op[2] = o[2];
    }
}

extern "C" void kernel_launch(void* const* d_in, const int* in_sizes, int n_in,
                              void* d_out, int out_size, void* d_ws, size_t ws_size,
                              hipStream_t stream) {
    const float* x      = (const float*)d_in[0];
    const float* conv_w = (const float*)d_in[1];
    const float* conv_b = (const float*)d_in[2];
    const float* gnw    = (const float*)d_in[3];
    const float* gnb    = (const float*)d_in[4];
    const float* scale  = (const float*)d_in[5];
    float* out = (float*)d_out;

    const size_t pl_bytes = (size_t)BATCH * COUT * HP * 64 * 4;   // 66.1 MB
    unsigned int* pl = (unsigned int*)d_ws;
    float* stats = (float*)((char*)d_ws + pl_bytes);              // 4 KB reserved
    _Float16* wT = (_Float16*)((char*)d_ws + pl_bytes + 4096);    // 147,456 B
    _Float16* xp = (_Float16*)((char*)d_ws + pl_bytes + 4096 + 147456); // 68.2 MB

    hipMemsetAsync(stats, 0, BATCH * NGROUPS * 2 * sizeof(float), stream);

    wt_kernel<<<(9 * COUT * CIN + 255) / 256, 256, 0, stream>>>(conv_w, wT);

    dim3 rgrid(HIN, BATCH);
    repack_kernel<<<rgrid, 256, 0, stream>>>(x, xp);

    dim3 grid(HP, BATCH);   // 63 x 32 = 2016 blocks
    conv_mfma_kernel<<<grid, 256, 0, stream>>>(xp, wT, conv_b, pl, stats);

    norm_pool_kernel<<<BATCH * COUT * 4, 256, 0, stream>>>(
        pl, stats, gnw, gnb, scale, out);
}